// Round 4
// baseline (413.189 us; speedup 1.0000x reference)
//
#include <hip/hip_runtime.h>
#include <hip/hip_bf16.h>
#include <math.h>

// Problem constants (from reference): B=4, T=8192, D=512, S=16
#define B_ 4
#define T_ 8192
#define D_ 512
#define S_ 16

// ---------------------------------------------------------------------------
// Reduce-scatter across a wave: input vals[16] per lane (partial sums),
// output: full 64-lane sum of splat s=(lane>>2)&15, returned in every lane.
// ---------------------------------------------------------------------------
__device__ __forceinline__ float reduce_scatter16(float vals[S_], int lane) {
  {
    const int bit = (lane >> 5) & 1;
#pragma unroll
    for (int i = 0; i < 8; ++i) {
      float send = bit ? vals[i] : vals[i + 8];
      float keep = bit ? vals[i + 8] : vals[i];
      vals[i] = keep + __shfl_xor(send, 32, 64);
    }
  }
  {
    const int bit = (lane >> 4) & 1;
#pragma unroll
    for (int i = 0; i < 4; ++i) {
      float send = bit ? vals[i] : vals[i + 4];
      float keep = bit ? vals[i + 4] : vals[i];
      vals[i] = keep + __shfl_xor(send, 16, 64);
    }
  }
  {
    const int bit = (lane >> 3) & 1;
#pragma unroll
    for (int i = 0; i < 2; ++i) {
      float send = bit ? vals[i] : vals[i + 2];
      float keep = bit ? vals[i + 2] : vals[i];
      vals[i] = keep + __shfl_xor(send, 8, 64);
    }
  }
  {
    const int bit = (lane >> 2) & 1;
    float send = bit ? vals[0] : vals[1];
    float keep = bit ? vals[1] : vals[0];
    float v = keep + __shfl_xor(send, 4, 64);
    v += __shfl_xor(v, 2, 64);
    v += __shfl_xor(v, 1, 64);
    return v;
  }
}

__device__ __forceinline__ float dot4(float4 a, float4 b) {
  return a.x * b.x + a.y * b.y + a.z * b.z + a.w * b.w;
}

__device__ __forceinline__ void fma4(float4& d, float a, float4 v) {
  d.x += a * v.x; d.y += a * v.y; d.z += a * v.z; d.w += a * v.w;
}

// ---------------------------------------------------------------------------
// Fused kernel 1: attn + token->splat aggregation. One wave per 32-token
// chunk (1024 waves: b = wid>>8, chunk = wid&255). Per token pair:
//   - softmax over splats (reduce-scatter + lane-bits-2..5 shuffles)
//   - write attn row
//   - broadcast the 16 attn values, FMA into register-resident ts partial
//     (lane owns d = 4*lane..+3 and 256+4*lane..+3 for ALL 16 splats)
// Flush once per wave via atomicAdd into memset-zeroed ts. x is read ONCE
// (was read twice by the unfused attn_k + ts_k => saves 64 MB HBM).
// VGPR ~340 (c_reg 128 + tsa 128 + x 32 + temps) -> 1 wave/SIMD, no spill.
// ---------------------------------------------------------------------------
__global__ __launch_bounds__(256, 1) void attn_ts_k(const float* __restrict__ x,
                                                    const float* __restrict__ centers,
                                                    const float* __restrict__ log_scales,
                                                    float* __restrict__ attn,
                                                    float* __restrict__ ts) {
  const int lane = threadIdx.x & 63;
  const int wid = (blockIdx.x << 2) + (threadIdx.x >> 6);  // 0..1023
  const int b = wid >> 8;                                  // 256 waves/batch
  const int t0 = (wid & 255) * (T_ / 256);                 // 32 tokens/wave
  const int myS = (lane >> 2) & 15;

  // centers in registers (128 VGPRs)
  float4 c_reg[S_][2];
#pragma unroll
  for (int s = 0; s < S_; ++s)
#pragma unroll
    for (int j = 0; j < 2; ++j)
      c_reg[s][j] = *(const float4*)(centers + s * D_ + (j << 8) + (lane << 2));

  float c2;
  {
    float vals[S_];
#pragma unroll
    for (int s = 0; s < S_; ++s)
      vals[s] = dot4(c_reg[s][0], c_reg[s][0]) + dot4(c_reg[s][1], c_reg[s][1]);
    c2 = reduce_scatter16(vals, lane);
  }
  const float sc = fminf(fmaxf(__expf(log_scales[myS]), 0.1f), 2.0f);
  const float inv2 = 0.5f / (sc * sc);

  // register-resident ts partial: 16 splats x 2 float4 (128 VGPRs)
  float4 tsa[S_][2];
#pragma unroll
  for (int s = 0; s < S_; ++s) {
    tsa[s][0] = make_float4(0.f, 0.f, 0.f, 0.f);
    tsa[s][1] = make_float4(0.f, 0.f, 0.f, 0.f);
  }

  const float* xr = x + ((size_t)b * T_ + t0) * D_;
  float* ar = attn + ((size_t)b * T_ + t0) * S_;

  // prefetch first token pair
  float4 na0 = *(const float4*)(xr + (lane << 2));
  float4 na1 = *(const float4*)(xr + 256 + (lane << 2));
  float4 nb0 = *(const float4*)(xr + 512 + (lane << 2));
  float4 nb1 = *(const float4*)(xr + 768 + (lane << 2));

#pragma unroll 1
  for (int tt = 0; tt < 32; tt += 2) {
    float4 a0 = na0, a1 = na1, b0 = nb0, b1 = nb1;
    if (tt + 2 < 32) {  // prefetch next pair (uniform branch)
      const float* nx = xr + (size_t)(tt + 2) * D_;
      na0 = *(const float4*)(nx + (lane << 2));
      na1 = *(const float4*)(nx + 256 + (lane << 2));
      nb0 = *(const float4*)(nx + 512 + (lane << 2));
      nb1 = *(const float4*)(nx + 768 + (lane << 2));
    }

    float x2a = dot4(a0, a0) + dot4(a1, a1);
    float x2b = dot4(b0, b0) + dot4(b1, b1);

    float va[S_], vb[S_];
#pragma unroll
    for (int s = 0; s < S_; ++s) {
      va[s] = x2a - 2.f * (dot4(a0, c_reg[s][0]) + dot4(a1, c_reg[s][1]));
      vb[s] = x2b - 2.f * (dot4(b0, c_reg[s][0]) + dot4(b1, c_reg[s][1]));
    }

    float ra = reduce_scatter16(va, lane);
    float rb = reduce_scatter16(vb, lane);
    float la = -(ra + c2) * inv2;
    float lb = -(rb + c2) * inv2;

    // softmax over splats (lane bits 2..5); two chains interleave
    float ma = la, mb = lb;
    ma = fmaxf(ma, __shfl_xor(ma, 4, 64));  mb = fmaxf(mb, __shfl_xor(mb, 4, 64));
    ma = fmaxf(ma, __shfl_xor(ma, 8, 64));  mb = fmaxf(mb, __shfl_xor(mb, 8, 64));
    ma = fmaxf(ma, __shfl_xor(ma, 16, 64)); mb = fmaxf(mb, __shfl_xor(mb, 16, 64));
    ma = fmaxf(ma, __shfl_xor(ma, 32, 64)); mb = fmaxf(mb, __shfl_xor(mb, 32, 64));
    float ea = __expf(la - ma), eb = __expf(lb - mb);
    float sa = ea, sb = eb;
    sa += __shfl_xor(sa, 4, 64);  sb += __shfl_xor(sb, 4, 64);
    sa += __shfl_xor(sa, 8, 64);  sb += __shfl_xor(sb, 8, 64);
    sa += __shfl_xor(sa, 16, 64); sb += __shfl_xor(sb, 16, 64);
    sa += __shfl_xor(sa, 32, 64); sb += __shfl_xor(sb, 32, 64);
    float aa = ea / sa, ab2 = eb / sb;  // this lane's attn for myS

    if ((lane & 3) == 0) {
      ar[(size_t)tt * S_ + myS] = aa;
      ar[(size_t)(tt + 1) * S_ + myS] = ab2;
    }

    // broadcast all 16 attn values, accumulate ts partial
#pragma unroll
    for (int s = 0; s < S_; ++s) {
      float as = __shfl(aa, s << 2, 64);
      float bs = __shfl(ab2, s << 2, 64);
      fma4(tsa[s][0], as, a0); fma4(tsa[s][1], as, a1);
      fma4(tsa[s][0], bs, b0); fma4(tsa[s][1], bs, b1);
    }
  }

  // flush ts partial (ts pre-zeroed by memset; region is L2-resident 128 KB)
  float* tb = ts + (size_t)b * S_ * D_;
#pragma unroll
  for (int s = 0; s < S_; ++s) {
#pragma unroll
    for (int j = 0; j < 2; ++j) {
      float* p = tb + s * D_ + (j << 8) + (lane << 2);
      atomicAdd(p + 0, tsa[s][j].x);
      atomicAdd(p + 1, tsa[s][j].y);
      atomicAdd(p + 2, tsa[s][j].z);
      atomicAdd(p + 3, tsa[s][j].w);
    }
  }
}

// ---------------------------------------------------------------------------
// Kernel 2 (x2): out[r,e] = sum_k in[r,k] * W[e,k]   (r = 0..63 = b*S+s)
// Split-K=4 reduced in LDS (deterministic). 512 blocks x 256 threads.
// ---------------------------------------------------------------------------
__global__ __launch_bounds__(256) void proj_k(const float* __restrict__ in,
                                              const float* __restrict__ W,
                                              float* __restrict__ out) {
  __shared__ float red[4][64];
  const int r = blockIdx.x >> 3;
  const int eb = blockIdx.x & 7;
  const int el = threadIdx.x & 63;
  const int kc = threadIdx.x >> 6;
  const int e = (eb << 6) + el;

  const float4* w4 = (const float4*)(W + (size_t)e * D_ + kc * 128);
  const float4* i4 = (const float4*)(in + (size_t)r * D_ + kc * 128);
  float acc = 0.f;
#pragma unroll
  for (int k = 0; k < 32; ++k) acc += dot4(w4[k], i4[k]);

  red[kc][el] = acc;
  __syncthreads();
  if (kc == 0)
    out[(size_t)r * D_ + e] = red[0][el] + red[1][el] + red[2][el] + red[3][el];
}

// ---------------------------------------------------------------------------
// Kernel 3: out[b,t,e] = sum_s attn[b,t,s] * ss_o[b,s,e]
// ss_o slice in registers (16 x float2); attn wave-uniform loads; coalesced
// float2 stores.
// ---------------------------------------------------------------------------
#define K4_TOK 64
__global__ __launch_bounds__(256) void out_k(const float* __restrict__ attn,
                                             const float* __restrict__ ss_o,
                                             float* __restrict__ out) {
  const int chunks = T_ / K4_TOK;  // 128
  const int b = blockIdx.x / chunks;
  const int t0 = (blockIdx.x % chunks) * K4_TOK;
  const int w = threadIdx.x >> 6;
  const int lane = threadIdx.x & 63;
  const int e0 = (w << 7) + (lane << 1);

  float2 ssf[S_];
  const float* sb = ss_o + (size_t)b * S_ * D_;
#pragma unroll
  for (int s = 0; s < S_; ++s) ssf[s] = *(const float2*)(sb + s * D_ + e0);

  const float4* ab = (const float4*)(attn + ((size_t)b * T_ + t0) * S_);
  float* ob = out + ((size_t)b * T_ + t0) * D_ + e0;

#pragma unroll 4
  for (int t = 0; t < K4_TOK; ++t) {
    float4 a0 = ab[t * 4 + 0], a1 = ab[t * 4 + 1];
    float4 a2 = ab[t * 4 + 2], a3 = ab[t * 4 + 3];
    float av[S_] = {a0.x, a0.y, a0.z, a0.w, a1.x, a1.y, a1.z, a1.w,
                    a2.x, a2.y, a2.z, a2.w, a3.x, a3.y, a3.z, a3.w};
    float2 acc = make_float2(0.f, 0.f);
#pragma unroll
    for (int s = 0; s < S_; ++s) {
      acc.x += av[s] * ssf[s].x;
      acc.y += av[s] * ssf[s].y;
    }
    *(float2*)(ob + (size_t)t * D_) = acc;
  }
}

// ---------------------------------------------------------------------------
extern "C" void kernel_launch(void* const* d_in, const int* in_sizes, int n_in,
                              void* d_out, int out_size, void* d_ws, size_t ws_size,
                              hipStream_t stream) {
  const float* x          = (const float*)d_in[0];  // [B,T,D]
  const float* centers    = (const float*)d_in[1];  // [S,D]
  const float* log_scales = (const float*)d_in[2];  // [S]
  const float* Wv         = (const float*)d_in[3];  // [D,D]
  const float* Wo         = (const float*)d_in[4];  // [D,D]
  float* out = (float*)d_out;                       // [B,T,D]

  // workspace layout (floats): attn | ts | tmp | ss_o
  float* attn = (float*)d_ws;                        // B*T*S   = 2 MB
  float* ts   = attn + (size_t)B_ * T_ * S_;         // B*S*D   = 128 KB
  float* tmp  = ts + (size_t)B_ * S_ * D_;           // B*S*D   = 128 KB
  float* ss_o = tmp + (size_t)B_ * S_ * D_;          // B*S*D   = 128 KB

  // zero only the atomic target (tiny, L2-resident fill)
  hipMemsetAsync(ts, 0, (size_t)B_ * S_ * D_ * sizeof(float), stream);

  attn_ts_k<<<256, 256, 0, stream>>>(x, centers, log_scales, attn, ts);
  proj_k<<<512, 256, 0, stream>>>(ts, Wv, tmp);    // tmp = ts @ Wv^T
  proj_k<<<512, 256, 0, stream>>>(tmp, Wo, ss_o);  // ss_o = tmp @ Wo^T
  out_k<<<B_ * (T_ / K4_TOK), 256, 0, stream>>>(attn, ss_o, out);
}

// Round 5
// 258.912 us; speedup vs baseline: 1.5959x; 1.5959x over previous
//
#include <hip/hip_runtime.h>
#include <hip/hip_bf16.h>
#include <math.h>

// Problem constants (from reference): B=4, T=8192, D=512, S=16
#define B_ 4
#define T_ 8192
#define D_ 512
#define S_ 16

// ---------------------------------------------------------------------------
// Reduce-scatter across a wave: input vals[16] per lane (partial sums),
// output: full 64-lane sum of splat s=(lane>>2)&15, returned in every lane.
// ---------------------------------------------------------------------------
__device__ __forceinline__ float reduce_scatter16(float vals[S_], int lane) {
  {
    const int bit = (lane >> 5) & 1;
#pragma unroll
    for (int i = 0; i < 8; ++i) {
      float send = bit ? vals[i] : vals[i + 8];
      float keep = bit ? vals[i + 8] : vals[i];
      vals[i] = keep + __shfl_xor(send, 32, 64);
    }
  }
  {
    const int bit = (lane >> 4) & 1;
#pragma unroll
    for (int i = 0; i < 4; ++i) {
      float send = bit ? vals[i] : vals[i + 4];
      float keep = bit ? vals[i + 4] : vals[i];
      vals[i] = keep + __shfl_xor(send, 16, 64);
    }
  }
  {
    const int bit = (lane >> 3) & 1;
#pragma unroll
    for (int i = 0; i < 2; ++i) {
      float send = bit ? vals[i] : vals[i + 2];
      float keep = bit ? vals[i + 2] : vals[i];
      vals[i] = keep + __shfl_xor(send, 8, 64);
    }
  }
  {
    const int bit = (lane >> 2) & 1;
    float send = bit ? vals[0] : vals[1];
    float keep = bit ? vals[1] : vals[0];
    float v = keep + __shfl_xor(send, 4, 64);
    v += __shfl_xor(v, 2, 64);
    v += __shfl_xor(v, 1, 64);
    return v;
  }
}

__device__ __forceinline__ float dot4(float4 a, float4 b) {
  return a.x * b.x + a.y * b.y + a.z * b.z + a.w * b.w;
}

__device__ __forceinline__ void fma4(float4& d, float a, float4 v) {
  d.x += a * v.x; d.y += a * v.y; d.z += a * v.z; d.w += a * v.w;
}

// ---------------------------------------------------------------------------
// Fused attn + token->splat aggregation, D split across wave PAIRS.
// Block = 4 waves = 2 pairs. Within a pair, wave h in {0,1} owns d-half
// [256h, 256h+256); lane owns float4 at d = 256h + 4*lane. Per-lane state:
// c_reg 16xfloat4 (64 VGPR) + tsa 16xfloat4 (64 VGPR) ~= 200 total — fits
// the 256 arch-VGPR budget (R4's full-row version needed ~340 and spilled
// to scratch: 133 MB writes, 297 us).
// Per 2 tokens: per-half logit partials -> 1 KB double-buffered LDS ->
// ONE barrier -> softmax (per-wave, lane bits 2..5) -> attn write (h==0)
// -> broadcast 16 attn vals -> tsa FMA. Next x prefetched BEFORE the
// barrier so the vmcnt drain overlaps the pipeline.
// Flush: cross-pair LDS pre-reduce (32 KB), then p==0 waves atomicAdd into
// the memset-zeroed, L2-resident 128 KB ts.
// ---------------------------------------------------------------------------
__global__ __launch_bounds__(256, 2) void attn_ts_k(const float* __restrict__ x,
                                                    const float* __restrict__ centers,
                                                    const float* __restrict__ log_scales,
                                                    float* __restrict__ attn,
                                                    float* __restrict__ ts) {
  __shared__ float red[2][2][2][2][S_];  // [pair][buf][tok][half][splat] 1 KB
  __shared__ float c2red[2][S_];
  __shared__ float fl[2][S_][256];       // cross-pair flush, 32 KB

  const int lane = threadIdx.x & 63;
  const int w = threadIdx.x >> 6;
  const int p = w >> 1;   // pair id
  const int h = w & 1;    // d-half
  const int myS = (lane >> 2) & 15;

  const int b = blockIdx.x >> 7;                 // 128 blocks per batch
  const int pp = ((blockIdx.x & 127) << 1) | p;  // pair index in batch, 0..255
  const int t0 = pp * 32;                        // 32 tokens per pair

  // centers for this half: 16 x float4 (64 VGPRs)
  float4 c_reg[S_];
#pragma unroll
  for (int s = 0; s < S_; ++s)
    c_reg[s] = *(const float4*)(centers + s * D_ + (h << 8) + (lane << 2));

  // full-D c2 via one block reduction (pair 0 writes, everyone reads)
  {
    float vals[S_];
#pragma unroll
    for (int s = 0; s < S_; ++s) vals[s] = dot4(c_reg[s], c_reg[s]);
    float part = reduce_scatter16(vals, lane);
    if (p == 0 && (lane & 3) == 0) c2red[h][myS] = part;
  }
  __syncthreads();
  const float c2 = c2red[0][myS] + c2red[1][myS];
  const float sc = fminf(fmaxf(__expf(log_scales[myS]), 0.1f), 2.0f);
  const float inv2 = 0.5f / (sc * sc);

  // ts partial for this half: 16 x float4 (64 VGPRs)
  float4 tsa[S_];
#pragma unroll
  for (int s = 0; s < S_; ++s) tsa[s] = make_float4(0.f, 0.f, 0.f, 0.f);

  const float* xr = x + ((size_t)b * T_ + t0) * D_ + (h << 8) + (lane << 2);
  float* ar = attn + ((size_t)b * T_ + t0) * S_;

  float4 xa = *(const float4*)(xr);
  float4 xb = *(const float4*)(xr + D_);
  float4 nxa = xa, nxb = xb;

#pragma unroll 1
  for (int it = 0; it < 16; ++it) {
    const int buf = it & 1;
    float x2a = dot4(xa, xa);
    float x2b = dot4(xb, xb);
    float va[S_], vb[S_];
#pragma unroll
    for (int s = 0; s < S_; ++s) {
      va[s] = x2a - 2.f * dot4(xa, c_reg[s]);
      vb[s] = x2b - 2.f * dot4(xb, c_reg[s]);
    }
    float ra = reduce_scatter16(va, lane);
    float rb = reduce_scatter16(vb, lane);
    if ((lane & 3) == 0) {
      red[p][buf][0][h][myS] = ra;
      red[p][buf][1][h][myS] = rb;
    }
    // prefetch next token pair BEFORE the barrier (drain overlaps pipeline)
    if (it + 1 < 16) {
      const float* nx = xr + (size_t)(2 * it + 2) * D_;
      nxa = *(const float4*)(nx);
      nxb = *(const float4*)(nx + D_);
    }
    __syncthreads();
    float fa = red[p][buf][0][0][myS] + red[p][buf][0][1][myS];
    float fb = red[p][buf][1][0][myS] + red[p][buf][1][1][myS];
    float la = -(fa + c2) * inv2;
    float lb = -(fb + c2) * inv2;

    float ma = la, mb = lb;
    ma = fmaxf(ma, __shfl_xor(ma, 4, 64));  mb = fmaxf(mb, __shfl_xor(mb, 4, 64));
    ma = fmaxf(ma, __shfl_xor(ma, 8, 64));  mb = fmaxf(mb, __shfl_xor(mb, 8, 64));
    ma = fmaxf(ma, __shfl_xor(ma, 16, 64)); mb = fmaxf(mb, __shfl_xor(mb, 16, 64));
    ma = fmaxf(ma, __shfl_xor(ma, 32, 64)); mb = fmaxf(mb, __shfl_xor(mb, 32, 64));
    float ea = __expf(la - ma), eb = __expf(lb - mb);
    float sa = ea, sb = eb;
    sa += __shfl_xor(sa, 4, 64);  sb += __shfl_xor(sb, 4, 64);
    sa += __shfl_xor(sa, 8, 64);  sb += __shfl_xor(sb, 8, 64);
    sa += __shfl_xor(sa, 16, 64); sb += __shfl_xor(sb, 16, 64);
    sa += __shfl_xor(sa, 32, 64); sb += __shfl_xor(sb, 32, 64);
    float aa = ea / sa, ab2 = eb / sb;

    if (h == 0 && (lane & 3) == 0) {
      ar[(size_t)(2 * it) * S_ + myS] = aa;
      ar[(size_t)(2 * it + 1) * S_ + myS] = ab2;
    }

    // broadcast all 16 attn values, FMA into this half's ts partial
#pragma unroll
    for (int s = 0; s < S_; ++s) {
      float as = __shfl(aa, s << 2, 64);
      float bs = __shfl(ab2, s << 2, 64);
      fma4(tsa[s], as, xa);
      fma4(tsa[s], bs, xb);
    }
    xa = nxa; xb = nxb;
  }

  // cross-pair pre-reduce in LDS, then atomic flush (halves atomic count)
  if (p == 1) {
#pragma unroll
    for (int s = 0; s < S_; ++s)
      *(float4*)&fl[h][s][lane << 2] = tsa[s];
  }
  __syncthreads();
  if (p == 0) {
    float* tb = ts + (size_t)b * S_ * D_ + (h << 8) + (lane << 2);
#pragma unroll
    for (int s = 0; s < S_; ++s) {
      float4 o = *(const float4*)&fl[h][s][lane << 2];
      atomicAdd(tb + s * D_ + 0, tsa[s].x + o.x);
      atomicAdd(tb + s * D_ + 1, tsa[s].y + o.y);
      atomicAdd(tb + s * D_ + 2, tsa[s].z + o.z);
      atomicAdd(tb + s * D_ + 3, tsa[s].w + o.w);
    }
  }
}

// ---------------------------------------------------------------------------
// Kernel 2 (x2): out[r,e] = sum_k in[r,k] * W[e,k]   (r = 0..63 = b*S+s)
// Split-K=4 reduced in LDS (deterministic). 512 blocks x 256 threads.
// ---------------------------------------------------------------------------
__global__ __launch_bounds__(256) void proj_k(const float* __restrict__ in,
                                              const float* __restrict__ W,
                                              float* __restrict__ out) {
  __shared__ float red[4][64];
  const int r = blockIdx.x >> 3;
  const int eb = blockIdx.x & 7;
  const int el = threadIdx.x & 63;
  const int kc = threadIdx.x >> 6;
  const int e = (eb << 6) + el;

  const float4* w4 = (const float4*)(W + (size_t)e * D_ + kc * 128);
  const float4* i4 = (const float4*)(in + (size_t)r * D_ + kc * 128);
  float acc = 0.f;
#pragma unroll
  for (int k = 0; k < 32; ++k) acc += dot4(w4[k], i4[k]);

  red[kc][el] = acc;
  __syncthreads();
  if (kc == 0)
    out[(size_t)r * D_ + e] = red[0][el] + red[1][el] + red[2][el] + red[3][el];
}

// ---------------------------------------------------------------------------
// Kernel 3: out[b,t,e] = sum_s attn[b,t,s] * ss_o[b,s,e]
// ss_o slice in registers (16 x float2); attn wave-uniform loads; coalesced
// float2 stores.
// ---------------------------------------------------------------------------
#define K4_TOK 64
__global__ __launch_bounds__(256) void out_k(const float* __restrict__ attn,
                                             const float* __restrict__ ss_o,
                                             float* __restrict__ out) {
  const int chunks = T_ / K4_TOK;  // 128
  const int b = blockIdx.x / chunks;
  const int t0 = (blockIdx.x % chunks) * K4_TOK;
  const int w = threadIdx.x >> 6;
  const int lane = threadIdx.x & 63;
  const int e0 = (w << 7) + (lane << 1);

  float2 ssf[S_];
  const float* sb = ss_o + (size_t)b * S_ * D_;
#pragma unroll
  for (int s = 0; s < S_; ++s) ssf[s] = *(const float2*)(sb + s * D_ + e0);

  const float4* ab = (const float4*)(attn + ((size_t)b * T_ + t0) * S_);
  float* ob = out + ((size_t)b * T_ + t0) * D_ + e0;

#pragma unroll 4
  for (int t = 0; t < K4_TOK; ++t) {
    float4 a0 = ab[t * 4 + 0], a1 = ab[t * 4 + 1];
    float4 a2 = ab[t * 4 + 2], a3 = ab[t * 4 + 3];
    float av[S_] = {a0.x, a0.y, a0.z, a0.w, a1.x, a1.y, a1.z, a1.w,
                    a2.x, a2.y, a2.z, a2.w, a3.x, a3.y, a3.z, a3.w};
    float2 acc = make_float2(0.f, 0.f);
#pragma unroll
    for (int s = 0; s < S_; ++s) {
      acc.x += av[s] * ssf[s].x;
      acc.y += av[s] * ssf[s].y;
    }
    *(float2*)(ob + (size_t)t * D_) = acc;
  }
}

// ---------------------------------------------------------------------------
extern "C" void kernel_launch(void* const* d_in, const int* in_sizes, int n_in,
                              void* d_out, int out_size, void* d_ws, size_t ws_size,
                              hipStream_t stream) {
  const float* x          = (const float*)d_in[0];  // [B,T,D]
  const float* centers    = (const float*)d_in[1];  // [S,D]
  const float* log_scales = (const float*)d_in[2];  // [S]
  const float* Wv         = (const float*)d_in[3];  // [D,D]
  const float* Wo         = (const float*)d_in[4];  // [D,D]
  float* out = (float*)d_out;                       // [B,T,D]

  // workspace layout (floats): attn | ts | tmp | ss_o
  float* attn = (float*)d_ws;                        // B*T*S   = 2 MB
  float* ts   = attn + (size_t)B_ * T_ * S_;         // B*S*D   = 128 KB
  float* tmp  = ts + (size_t)B_ * S_ * D_;           // B*S*D   = 128 KB
  float* ss_o = tmp + (size_t)B_ * S_ * D_;          // B*S*D   = 128 KB

  // zero only the atomic target (tiny, L2-resident fill)
  hipMemsetAsync(ts, 0, (size_t)B_ * S_ * D_ * sizeof(float), stream);

  attn_ts_k<<<512, 256, 0, stream>>>(x, centers, log_scales, attn, ts);
  proj_k<<<512, 256, 0, stream>>>(ts, Wv, tmp);    // tmp = ts @ Wv^T
  proj_k<<<512, 256, 0, stream>>>(tmp, Wo, ss_o);  // ss_o = tmp @ Wo^T
  out_k<<<B_ * (T_ / K4_TOK), 256, 0, stream>>>(attn, ss_o, out);
}

// Round 6
// 178.464 us; speedup vs baseline: 2.3153x; 1.4508x over previous
//
#include <hip/hip_runtime.h>
#include <hip/hip_bf16.h>
#include <math.h>

// Problem constants (from reference): B=4, T=8192, D=512, S=16
#define B_ 4
#define T_ 8192
#define D_ 512
#define S_ 16

// ---------------------------------------------------------------------------
// Reduce-scatter across a wave: input vals[16] per lane (partial sums),
// output: full 64-lane sum of splat s=(lane>>2)&15, returned in every lane.
// ---------------------------------------------------------------------------
__device__ __forceinline__ float reduce_scatter16(float vals[S_], int lane) {
  {
    const int bit = (lane >> 5) & 1;
#pragma unroll
    for (int i = 0; i < 8; ++i) {
      float send = bit ? vals[i] : vals[i + 8];
      float keep = bit ? vals[i + 8] : vals[i];
      vals[i] = keep + __shfl_xor(send, 32, 64);
    }
  }
  {
    const int bit = (lane >> 4) & 1;
#pragma unroll
    for (int i = 0; i < 4; ++i) {
      float send = bit ? vals[i] : vals[i + 4];
      float keep = bit ? vals[i + 4] : vals[i];
      vals[i] = keep + __shfl_xor(send, 16, 64);
    }
  }
  {
    const int bit = (lane >> 3) & 1;
#pragma unroll
    for (int i = 0; i < 2; ++i) {
      float send = bit ? vals[i] : vals[i + 2];
      float keep = bit ? vals[i + 2] : vals[i];
      vals[i] = keep + __shfl_xor(send, 8, 64);
    }
  }
  {
    const int bit = (lane >> 2) & 1;
    float send = bit ? vals[0] : vals[1];
    float keep = bit ? vals[1] : vals[0];
    float v = keep + __shfl_xor(send, 4, 64);
    v += __shfl_xor(v, 2, 64);
    v += __shfl_xor(v, 1, 64);
    return v;
  }
}

__device__ __forceinline__ float dot4(float4 a, float4 b) {
  return a.x * b.x + a.y * b.y + a.z * b.z + a.w * b.w;
}

// ---------------------------------------------------------------------------
// Fused attn + token->splat aggregation, TWO PHASES per 64-token chunk.
// Block = 256 threads (4 waves); 512 blocks = B * T/64 chunks.
//
// Phase A (== R3's proven attn_k inner loop, c_reg 128 VGPRs): wave w
// computes softmax for tokens t0+16w..+15, writes attn to global AND to a
// 4 KB LDS slab. NO ts accumulation in registers (that's what spilled in
// R4/R5: c_reg + tsa cannot co-exist under the 256 arch-VGPR file).
//
// Phase B (c_reg dead, ~60 VGPRs live): one barrier; thread owns columns
// d=tid and d+256; re-streams the chunk's x rows (L2/L3-hot from phase A,
// not HBM) against LDS-broadcast attn; 32 atomicAdds into L2-resident ts.
// ---------------------------------------------------------------------------
__global__ __launch_bounds__(256, 2) void attn_ts_k(const float* __restrict__ x,
                                                    const float* __restrict__ centers,
                                                    const float* __restrict__ log_scales,
                                                    float* __restrict__ attn,
                                                    float* __restrict__ ts) {
  __shared__ __align__(16) float a_s[64][S_];  // 4 KB
  const int lane = threadIdx.x & 63;
  const int w = threadIdx.x >> 6;  // 0..3
  const int myS = (lane >> 2) & 15;
  const int b = blockIdx.x >> 7;          // 128 chunks per batch
  const int t0 = (blockIdx.x & 127) * 64; // 64 tokens per block

  // ---- Phase A ----
  {
    // centers in registers (128 VGPRs)
    float4 c_reg[S_][2];
#pragma unroll
    for (int s = 0; s < S_; ++s)
#pragma unroll
      for (int j = 0; j < 2; ++j)
        c_reg[s][j] = *(const float4*)(centers + s * D_ + (j << 8) + (lane << 2));

    float c2;
    {
      float vals[S_];
#pragma unroll
      for (int s = 0; s < S_; ++s)
        vals[s] = dot4(c_reg[s][0], c_reg[s][0]) + dot4(c_reg[s][1], c_reg[s][1]);
      c2 = reduce_scatter16(vals, lane);
    }
    const float sc = fminf(fmaxf(__expf(log_scales[myS]), 0.1f), 2.0f);
    const float inv2 = 0.5f / (sc * sc);

    const int tw = t0 + (w << 4);  // this wave's 16 tokens
    const float* xr = x + ((size_t)b * T_ + tw) * D_;
    float* ar = attn + ((size_t)b * T_ + tw) * S_;

    // prefetch first token pair
    float4 na0 = *(const float4*)(xr + (lane << 2));
    float4 na1 = *(const float4*)(xr + 256 + (lane << 2));
    float4 nb0 = *(const float4*)(xr + 512 + (lane << 2));
    float4 nb1 = *(const float4*)(xr + 768 + (lane << 2));

#pragma unroll 1
    for (int tt = 0; tt < 16; tt += 2) {
      float4 a0 = na0, a1 = na1, b0 = nb0, b1 = nb1;
      if (tt + 2 < 16) {  // prefetch next pair (uniform branch)
        const float* nx = xr + (size_t)(tt + 2) * D_;
        na0 = *(const float4*)(nx + (lane << 2));
        na1 = *(const float4*)(nx + 256 + (lane << 2));
        nb0 = *(const float4*)(nx + 512 + (lane << 2));
        nb1 = *(const float4*)(nx + 768 + (lane << 2));
      }

      float x2a = dot4(a0, a0) + dot4(a1, a1);
      float x2b = dot4(b0, b0) + dot4(b1, b1);

      float va[S_], vb[S_];
#pragma unroll
      for (int s = 0; s < S_; ++s) {
        va[s] = x2a - 2.f * (dot4(a0, c_reg[s][0]) + dot4(a1, c_reg[s][1]));
        vb[s] = x2b - 2.f * (dot4(b0, c_reg[s][0]) + dot4(b1, c_reg[s][1]));
      }

      float ra = reduce_scatter16(va, lane);
      float rb = reduce_scatter16(vb, lane);
      float la = -(ra + c2) * inv2;
      float lb = -(rb + c2) * inv2;

      float ma = la, mb = lb;
      ma = fmaxf(ma, __shfl_xor(ma, 4, 64));  mb = fmaxf(mb, __shfl_xor(mb, 4, 64));
      ma = fmaxf(ma, __shfl_xor(ma, 8, 64));  mb = fmaxf(mb, __shfl_xor(mb, 8, 64));
      ma = fmaxf(ma, __shfl_xor(ma, 16, 64)); mb = fmaxf(mb, __shfl_xor(mb, 16, 64));
      ma = fmaxf(ma, __shfl_xor(ma, 32, 64)); mb = fmaxf(mb, __shfl_xor(mb, 32, 64));
      float ea = __expf(la - ma), eb = __expf(lb - mb);
      float sa = ea, sb = eb;
      sa += __shfl_xor(sa, 4, 64);  sb += __shfl_xor(sb, 4, 64);
      sa += __shfl_xor(sa, 8, 64);  sb += __shfl_xor(sb, 8, 64);
      sa += __shfl_xor(sa, 16, 64); sb += __shfl_xor(sb, 16, 64);
      sa += __shfl_xor(sa, 32, 64); sb += __shfl_xor(sb, 32, 64);
      float aa = ea / sa, ab2 = eb / sb;

      if ((lane & 3) == 0) {
        ar[(size_t)tt * S_ + myS] = aa;
        ar[(size_t)(tt + 1) * S_ + myS] = ab2;
        a_s[(w << 4) + tt][myS] = aa;
        a_s[(w << 4) + tt + 1][myS] = ab2;
      }
    }
  }  // c_reg dies here

  __syncthreads();

  // ---- Phase B ----
  {
    const int d = threadIdx.x;  // owns cols d and d+256
    float2 acc[S_];
#pragma unroll
    for (int s = 0; s < S_; ++s) acc[s] = make_float2(0.f, 0.f);

    const float* xb = x + ((size_t)b * T_ + t0) * D_;

#pragma unroll 8
    for (int t = 0; t < 64; ++t) {
      float xv0 = xb[(size_t)t * D_ + d];
      float xv1 = xb[(size_t)t * D_ + d + 256];
      const float4* ap = (const float4*)a_s[t];  // LDS broadcast
      float4 q0 = ap[0], q1 = ap[1], q2 = ap[2], q3 = ap[3];
      float av[S_] = {q0.x, q0.y, q0.z, q0.w, q1.x, q1.y, q1.z, q1.w,
                      q2.x, q2.y, q2.z, q2.w, q3.x, q3.y, q3.z, q3.w};
#pragma unroll
      for (int s = 0; s < S_; ++s) {
        acc[s].x += av[s] * xv0;
        acc[s].y += av[s] * xv1;
      }
    }

    float* tb = ts + (size_t)b * S_ * D_;
#pragma unroll
    for (int s = 0; s < S_; ++s) {
      atomicAdd(tb + s * D_ + d, acc[s].x);
      atomicAdd(tb + s * D_ + d + 256, acc[s].y);
    }
  }
}

// ---------------------------------------------------------------------------
// Kernel 2 (x2): out[r,e] = sum_k in[r,k] * W[e,k]   (r = 0..63 = b*S+s)
// Split-K=4 reduced in LDS (deterministic). 512 blocks x 256 threads.
// ---------------------------------------------------------------------------
__global__ __launch_bounds__(256) void proj_k(const float* __restrict__ in,
                                              const float* __restrict__ W,
                                              float* __restrict__ out) {
  __shared__ float red[4][64];
  const int r = blockIdx.x >> 3;
  const int eb = blockIdx.x & 7;
  const int el = threadIdx.x & 63;
  const int kc = threadIdx.x >> 6;
  const int e = (eb << 6) + el;

  const float4* w4 = (const float4*)(W + (size_t)e * D_ + kc * 128);
  const float4* i4 = (const float4*)(in + (size_t)r * D_ + kc * 128);
  float acc = 0.f;
#pragma unroll
  for (int k = 0; k < 32; ++k) acc += dot4(w4[k], i4[k]);

  red[kc][el] = acc;
  __syncthreads();
  if (kc == 0)
    out[(size_t)r * D_ + e] = red[0][el] + red[1][el] + red[2][el] + red[3][el];
}

// ---------------------------------------------------------------------------
// Kernel 3: out[b,t,e] = sum_s attn[b,t,s] * ss_o[b,s,e]
// ss_o slice in registers (16 x float2); attn wave-uniform loads; coalesced
// float2 stores.
// ---------------------------------------------------------------------------
#define K4_TOK 64
__global__ __launch_bounds__(256) void out_k(const float* __restrict__ attn,
                                             const float* __restrict__ ss_o,
                                             float* __restrict__ out) {
  const int chunks = T_ / K4_TOK;  // 128
  const int b = blockIdx.x / chunks;
  const int t0 = (blockIdx.x % chunks) * K4_TOK;
  const int w = threadIdx.x >> 6;
  const int lane = threadIdx.x & 63;
  const int e0 = (w << 7) + (lane << 1);

  float2 ssf[S_];
  const float* sb = ss_o + (size_t)b * S_ * D_;
#pragma unroll
  for (int s = 0; s < S_; ++s) ssf[s] = *(const float2*)(sb + s * D_ + e0);

  const float4* ab = (const float4*)(attn + ((size_t)b * T_ + t0) * S_);
  float* ob = out + ((size_t)b * T_ + t0) * D_ + e0;

#pragma unroll 4
  for (int t = 0; t < K4_TOK; ++t) {
    float4 a0 = ab[t * 4 + 0], a1 = ab[t * 4 + 1];
    float4 a2 = ab[t * 4 + 2], a3 = ab[t * 4 + 3];
    float av[S_] = {a0.x, a0.y, a0.z, a0.w, a1.x, a1.y, a1.z, a1.w,
                    a2.x, a2.y, a2.z, a2.w, a3.x, a3.y, a3.z, a3.w};
    float2 acc = make_float2(0.f, 0.f);
#pragma unroll
    for (int s = 0; s < S_; ++s) {
      acc.x += av[s] * ssf[s].x;
      acc.y += av[s] * ssf[s].y;
    }
    *(float2*)(ob + (size_t)t * D_) = acc;
  }
}

// ---------------------------------------------------------------------------
extern "C" void kernel_launch(void* const* d_in, const int* in_sizes, int n_in,
                              void* d_out, int out_size, void* d_ws, size_t ws_size,
                              hipStream_t stream) {
  const float* x          = (const float*)d_in[0];  // [B,T,D]
  const float* centers    = (const float*)d_in[1];  // [S,D]
  const float* log_scales = (const float*)d_in[2];  // [S]
  const float* Wv         = (const float*)d_in[3];  // [D,D]
  const float* Wo         = (const float*)d_in[4];  // [D,D]
  float* out = (float*)d_out;                       // [B,T,D]

  // workspace layout (floats): attn | ts | tmp | ss_o
  float* attn = (float*)d_ws;                        // B*T*S   = 2 MB
  float* ts   = attn + (size_t)B_ * T_ * S_;         // B*S*D   = 128 KB
  float* tmp  = ts + (size_t)B_ * S_ * D_;           // B*S*D   = 128 KB
  float* ss_o = tmp + (size_t)B_ * S_ * D_;          // B*S*D   = 128 KB

  // zero only the atomic target (tiny, L2-resident fill)
  hipMemsetAsync(ts, 0, (size_t)B_ * S_ * D_ * sizeof(float), stream);

  attn_ts_k<<<512, 256, 0, stream>>>(x, centers, log_scales, attn, ts);
  proj_k<<<512, 256, 0, stream>>>(ts, Wv, tmp);    // tmp = ts @ Wv^T
  proj_k<<<512, 256, 0, stream>>>(tmp, Wo, ss_o);  // ss_o = tmp @ Wo^T
  out_k<<<B_ * (T_ / K4_TOK), 256, 0, stream>>>(attn, ss_o, out);
}